// Round 3
// baseline (1422.493 us; speedup 1.0000x reference)
//
#include <hip/hip_runtime.h>
#include <hip/hip_bf16.h>

#define NL 4
#define NH 16
#define DM 1024
#define DHD 64
#define NV 32000
#define NB 2
#define NS 2048
#define NM (NB * NS)   // 4096 rows

typedef __attribute__((ext_vector_type(8))) short v8s;   // 8 bf16 (4 VGPRs) MFMA A/B frag
typedef __attribute__((ext_vector_type(4))) float v4f;   // MFMA C/D frag

#define MFMA(a, b, c) __builtin_amdgcn_mfma_f32_16x16x32_bf16(a, b, c, 0, 0, 0)

__device__ __forceinline__ short f2bf(float x) {
    __hip_bfloat16 h = __float2bfloat16(x);   // RNE
    return *reinterpret_cast<short*>(&h);
}
__device__ __forceinline__ float wave_sum(float v) {
    v += __shfl_xor(v, 32); v += __shfl_xor(v, 16); v += __shfl_xor(v, 8);
    v += __shfl_xor(v, 4);  v += __shfl_xor(v, 2);  v += __shfl_xor(v, 1);
    return v;
}
__device__ __forceinline__ float wave_max(float v) {
    v = fmaxf(v, __shfl_xor(v, 32)); v = fmaxf(v, __shfl_xor(v, 16));
    v = fmaxf(v, __shfl_xor(v, 8));  v = fmaxf(v, __shfl_xor(v, 4));
    v = fmaxf(v, __shfl_xor(v, 2));  v = fmaxf(v, __shfl_xor(v, 1));
    return v;
}

// ---------------- one-time weight prep (per call; graph-safe) ----------------
// Wq/Wk/Wv [LH][1024][64] fp32 -> WT bf16 [which*64+lh][64 dh][1024 k]
__global__ __launch_bounds__(256) void wqkv_transpose(
    const float* __restrict__ Wq, const float* __restrict__ Wk,
    const float* __restrict__ Wv, __hip_bfloat16* __restrict__ WT)
{
    __shared__ float T[64][68];
    const int t = threadIdx.x;
    const int k0 = blockIdx.x * 64;
    const int y = blockIdx.y;                 // which*64 + lh
    const int which = y >> 6, lh = y & 63;
    const float* W = (which == 0 ? Wq : which == 1 ? Wk : Wv)
                     + ((size_t)lh * DM + k0) * DHD;
#pragma unroll
    for (int i = 0; i < 4; ++i) {
        const int f = t + i * 256;            // 1024 float4 = 64 k-rows x 16
        const int kr = f >> 4, c = (f & 15) * 4;
        float4 w4 = *(const float4*)&W[(size_t)kr * DHD + c];
        T[kr][c + 0] = w4.x; T[kr][c + 1] = w4.y;
        T[kr][c + 2] = w4.z; T[kr][c + 3] = w4.w;
    }
    __syncthreads();
#pragma unroll
    for (int i = 0; i < 2; ++i) {
        const int f = t + i * 256;            // 512 chunks: 64 n-rows x 8
        const int n = f >> 3, c = (f & 7) * 8;
        short tmp[8];
#pragma unroll
        for (int j = 0; j < 8; ++j) tmp[j] = f2bf(T[c + j][n]);
        *(float4*)&WT[(((size_t)y) * 64 + n) * DM + k0 + c] = *(float4*)tmp;
    }
}

// Wffn [L][1024][1024] fp32 -> WT bf16 [l][1024 n][1024 k]
__global__ __launch_bounds__(256) void wffn_transpose(
    const float* __restrict__ Wffn, __hip_bfloat16* __restrict__ WT)
{
    __shared__ float T[64][68];
    const int t = threadIdx.x;
    const int k0 = blockIdx.x * 64, n0 = blockIdx.y * 64, l = blockIdx.z;
    const float* W = Wffn + ((size_t)l * DM + k0) * DM + n0;
#pragma unroll
    for (int i = 0; i < 4; ++i) {
        const int f = t + i * 256;
        const int kr = f >> 4, c = (f & 15) * 4;
        float4 w4 = *(const float4*)&W[(size_t)kr * DM + c];
        T[kr][c + 0] = w4.x; T[kr][c + 1] = w4.y;
        T[kr][c + 2] = w4.z; T[kr][c + 3] = w4.w;
    }
    __syncthreads();
#pragma unroll
    for (int i = 0; i < 2; ++i) {
        const int f = t + i * 256;
        const int n = f >> 3, c = (f & 7) * 8;
        short tmp[8];
#pragma unroll
        for (int j = 0; j < 8; ++j) tmp[j] = f2bf(T[c + j][n]);
        *(float4*)&WT[((size_t)l * DM + n0 + n) * DM + k0 + c] = *(float4*)tmp;
    }
}

__global__ __launch_bounds__(256) void convert_x0(
    const float* __restrict__ X, __hip_bfloat16* __restrict__ Xh)
{
    const size_t i = ((size_t)blockIdx.x * 256 + threadIdx.x) * 4;
    float4 x = *(const float4*)&X[i];
    union { short s[4]; float2 f2; } hb;
    hb.s[0] = f2bf(x.x); hb.s[1] = f2bf(x.y); hb.s[2] = f2bf(x.z); hb.s[3] = f2bf(x.w);
    *(float2*)&Xh[i] = hb.f2;
}

// ---------------- QKV projection (MFMA, pipelined staging) ----------------
// grid (32, 16): logical block = 128 rows x 192 cols (q|k|v of head h), K=1024.
// (m,h) remapped so each XCD's resident cell = 8 m-tiles x 8 heads:
// W/XCD = 3 MB + X/XCD = 2 MB ~ L2-resident.
// Q/K outputs staged via LDS -> full-line float4 row writes.
__global__ __launch_bounds__(256, 2) void qkv_gemm(
    const __hip_bfloat16* __restrict__ Xh, const __hip_bfloat16* __restrict__ WT,
    const float* __restrict__ bq, const float* __restrict__ bk,
    const float* __restrict__ bv,
    __hip_bfloat16* __restrict__ Q, __hip_bfloat16* __restrict__ K,
    __hip_bfloat16* __restrict__ Vt, int layer)
{
    __shared__ short As[128 * 72];   // X tile [128 m][64 k]; epilogue: Q [128 m][64 dh]
    __shared__ short Bs[192 * 72];   // W^T tile [192 n][64 k]; epilogue: K [128 m][64 dh]
    __shared__ short Vst[64 * 136];  // epilogue: V^T [64 d][128 s]
    const int t = threadIdx.x;
    const int wave = t >> 6, lane = t & 63, l15 = lane & 15, quad = lane >> 4;
    const int id = blockIdx.y * 32 + blockIdx.x;       // XCD = id % 8
    const int x8 = id & 7, j = id >> 3;
    const int m0 = ((x8 & 3) * 8 + (j & 7)) * 128;     // 8 m-tiles per XCD cell
    const int h = (x8 >> 2) * 8 + (j >> 3);            // 8 heads per XCD cell
    const int lh = layer * NH + h;
    const int arow = t >> 3, ac = (t & 7) * 8;

    v4f acc[2][12];
#pragma unroll
    for (int i = 0; i < 2; ++i)
#pragma unroll
        for (int j2 = 0; j2 < 12; ++j2) acc[i][j2] = 0.f;

    float4 ap[4], bp[6];
#pragma unroll
    for (int i = 0; i < 4; ++i)
        ap[i] = *(const float4*)&Xh[(size_t)(m0 + arow + i * 32) * DM + ac];
#pragma unroll
    for (int i = 0; i < 6; ++i) {
        const int row = arow + i * 32;
        const int which = row >> 6, dh = row & 63;
        bp[i] = *(const float4*)&WT[(((size_t)which * 64 + lh) * 64 + dh) * DM + ac];
    }

    for (int k0 = 0; k0 < DM; k0 += 64) {
        __syncthreads();
#pragma unroll
        for (int i = 0; i < 4; ++i) *(float4*)&As[(arow + i * 32) * 72 + ac] = ap[i];
#pragma unroll
        for (int i = 0; i < 6; ++i) *(float4*)&Bs[(arow + i * 32) * 72 + ac] = bp[i];
        __syncthreads();
        if (k0 + 64 < DM) {                   // prefetch next k-chunk during compute
            const int kn = k0 + 64;
#pragma unroll
            for (int i = 0; i < 4; ++i)
                ap[i] = *(const float4*)&Xh[(size_t)(m0 + arow + i * 32) * DM + kn + ac];
#pragma unroll
            for (int i = 0; i < 6; ++i) {
                const int row = arow + i * 32;
                const int which = row >> 6, dh = row & 63;
                bp[i] = *(const float4*)&WT[(((size_t)which * 64 + lh) * 64 + dh) * DM + kn + ac];
            }
        }

        v8s af[2][2];
#pragma unroll
        for (int rt = 0; rt < 2; ++rt)
#pragma unroll
            for (int kh = 0; kh < 2; ++kh)
                af[rt][kh] = *(const v8s*)&As[(wave * 32 + rt * 16 + l15) * 72 + kh * 32 + quad * 8];
#pragma unroll
        for (int ct = 0; ct < 12; ++ct) {
            v8s b0 = *(const v8s*)&Bs[(ct * 16 + l15) * 72 + quad * 8];
            v8s b1 = *(const v8s*)&Bs[(ct * 16 + l15) * 72 + 32 + quad * 8];
#pragma unroll
            for (int rt = 0; rt < 2; ++rt) {
                acc[rt][ct] = MFMA(af[rt][0], b0, acc[rt][ct]);
                acc[rt][ct] = MFMA(af[rt][1], b1, acc[rt][ct]);
            }
        }
    }

    // ---- epilogue: stage Q->As, K->Bs, V^T->Vst; then full-line coalesced writes ----
    __syncthreads();                      // all MFMA frag reads of As/Bs done
#pragma unroll
    for (int ct = 0; ct < 4; ++ct) {      // Q: [m][dh]
        const float bias = bq[(size_t)lh * DHD + ct * 16 + l15];
#pragma unroll
        for (int rt = 0; rt < 2; ++rt)
#pragma unroll
            for (int r = 0; r < 4; ++r) {
                const int row = wave * 32 + rt * 16 + quad * 4 + r;
                As[row * 72 + ct * 16 + l15] = f2bf(acc[rt][ct][r] + bias);
            }
    }
#pragma unroll
    for (int ct = 4; ct < 8; ++ct) {      // K: [m][dh]
        const float bias = bk[(size_t)lh * DHD + (ct - 4) * 16 + l15];
#pragma unroll
        for (int rt = 0; rt < 2; ++rt)
#pragma unroll
            for (int r = 0; r < 4; ++r) {
                const int row = wave * 32 + rt * 16 + quad * 4 + r;
                Bs[row * 72 + (ct - 4) * 16 + l15] = f2bf(acc[rt][ct][r] + bias);
            }
    }
#pragma unroll
    for (int ct = 8; ct < 12; ++ct) {     // V^T: [d][s]
        const int d = (ct - 8) * 16 + l15;
        const float bias = bv[(size_t)lh * DHD + d];
#pragma unroll
        for (int rt = 0; rt < 2; ++rt)
#pragma unroll
            for (int r = 0; r < 4; ++r) {
                const int srow = wave * 32 + rt * 16 + quad * 4 + r;
                Vst[d * 136 + srow] = f2bf(acc[rt][ct][r] + bias);
            }
    }
    __syncthreads();
#pragma unroll
    for (int i = 0; i < 4; ++i) {         // Q,K: 128 rows x 8 float4 (full 128-B rows)
        const int f = t + i * 256;
        const int row = f >> 3, c = (f & 7) * 8;
        const int m = m0 + row, bb = m >> 11, s = m & (NS - 1);
        const size_t base = ((size_t)(bb * NH + h) * NS + s) * DHD + c;
        *(float4*)&Q[base] = *(const float4*)&As[row * 72 + c];
        *(float4*)&K[base] = *(const float4*)&Bs[row * 72 + c];
    }
    const int bblk = m0 >> 11;            // block never spans batch (2048 % 128 == 0)
    const int s0 = m0 & (NS - 1);
    const size_t vtb = (size_t)(bblk * NH + h) * DHD * NS;
#pragma unroll
    for (int i = 0; i < 4; ++i) {         // V^T: 64 d-rows x 16 float4
        const int f = t + i * 256;
        const int d = f >> 4, c = (f & 15) * 8;
        *(float4*)&Vt[vtb + (size_t)d * NS + s0 + c] = *(const float4*)&Vst[d * 136 + c];
    }
}

// ---------------- attention (MFMA flash, faithful softmax-then-tril) ----------------
// grid (32 bh, 16 y): block = 128 q rows, 4 waves x 32 rows.
// blockIdx.x = bh -> all q-tiles of one (b,h) on ONE XCD (K/V L2-resident; FETCH
// is compulsory-only, verified round 2). bi = (y<8)?y:23-y balances PV work.
// SOFTWARE PIPELINE (round-3 change): iteration `it` computes QK^T(it) AND the
// exp/P/PV finish of tile it-1 -- two independent instruction streams that
// overlap (MFMA pipe vs TRANS/LDS pipe). K double-buffered, V triple-buffered
// (V is consumed one iteration later than K). ONE barrier per tile (was 2).
// FIXED-max softmax (scores O(1)); denominator over ALL tiles (faithful bug);
// tril masks P only; PV skipped for fully-masked tiles.
__global__ __launch_bounds__(256, 2) void attn_kernel(
    const __hip_bfloat16* __restrict__ Q, const __hip_bfloat16* __restrict__ K,
    const __hip_bfloat16* __restrict__ Vt, float* __restrict__ Z)
{
    // 2*K(64x72) + 3*V(64x72) + P(128x72) shorts = 64512 B (< 64 KiB cap)
    __shared__ short SMEM[5 * 64 * 72 + 128 * 72];
    short* Kb0 = SMEM;                   // [2][4608]
    short* Vb0 = SMEM + 2 * 64 * 72;     // [3][4608]
    short* Ps  = SMEM + 5 * 64 * 72;     // [128][72] wave-private strips
    const int t = threadIdx.x;
    const int w = t >> 6, lane = t & 63, l15 = lane & 15, quad = lane >> 4;
    const int bh = blockIdx.x;
    const int y = blockIdx.y;
    const int bi = (y < 8) ? y : (23 - y);           // co-resident pair sums to 15
    const int i0 = bi * 128;
    const int b = bh >> 4, h = bh & 15;
    const size_t qkb = (size_t)bh * NS * DHD;
    const size_t vtb = (size_t)bh * DHD * NS;
    const int arow = t >> 3, ac = (t & 7) * 8;
    const int ktd = 2 * bi + 1;                      // last tile with PV (>=1 always)

    // Q fragments (A-operand), loop-invariant, straight from global
    v8s qf[2][2];
#pragma unroll
    for (int rt = 0; rt < 2; ++rt) {
        const size_t qrow = qkb + (size_t)(i0 + w * 32 + rt * 16 + l15) * DHD + quad * 8;
        qf[rt][0] = *(const v8s*)&Q[qrow];
        qf[rt][1] = *(const v8s*)&Q[qrow + 32];
    }

    v4f o[2][4];
    float lpart[2][4];
#pragma unroll
    for (int rt = 0; rt < 2; ++rt)
#pragma unroll
        for (int i = 0; i < 4; ++i) { o[rt][i] = 0.f; lpart[rt][i] = 0.f; }

    // prologue: tile 0 -> LDS slot 0; tile 1 -> regs. (tiles 0,1 always have PV)
    float4 kf[2], vf[2];
#pragma unroll
    for (int i = 0; i < 2; ++i) {
        const int row = arow + i * 32;
        kf[i] = *(const float4*)&K[qkb + (size_t)row * DHD + ac];
        vf[i] = *(const float4*)&Vt[vtb + (size_t)row * NS + ac];
    }
#pragma unroll
    for (int i = 0; i < 2; ++i) {
        const int row = arow + i * 32;
        *(float4*)&Kb0[row * 72 + ac] = kf[i];
        *(float4*)&Vb0[row * 72 + ac] = vf[i];
    }
#pragma unroll
    for (int i = 0; i < 2; ++i) {
        const int row = arow + i * 32;
        kf[i] = *(const float4*)&K[qkb + (size_t)(64 + row) * DHD + ac];
        vf[i] = *(const float4*)&Vt[vtb + (size_t)row * NS + 64 + ac];
    }
    __syncthreads();

    int vw = 1;    // V slot of tile it+1 (write)
    int vr = 2;    // V slot of tile it-1 (read); valid from it=1

    // finish tile p: exp -> denominators; masked P -> PV
    auto FINISH = [&](int p, v4f (&s)[2][4]) {
#pragma unroll
        for (int rt = 0; rt < 2; ++rt) {
#pragma unroll
            for (int ct = 0; ct < 4; ++ct)
#pragma unroll
                for (int r = 0; r < 4; ++r)
                    s[rt][ct][r] = __expf(s[rt][ct][r] * 0.125f);
#pragma unroll
            for (int r = 0; r < 4; ++r)
                lpart[rt][r] += s[rt][0][r] + s[rt][1][r] + s[rt][2][r] + s[rt][3][r];
        }
        if (p <= ktd) {
            const int dk = p - 2 * bi;   // 0/1 on diagonal tiles, negative before
            const short* Vs = Vb0 + vr * 4608;
#pragma unroll
            for (int rt = 0; rt < 2; ++rt)
#pragma unroll
                for (int ct = 0; ct < 4; ++ct)
#pragma unroll
                    for (int r = 0; r < 4; ++r) {
                        const int rowl = w * 32 + rt * 16 + quad * 4 + r;
                        const int col = ct * 16 + l15;
                        float pvv = s[rt][ct][r];
                        if (dk >= 0 && dk * 64 + col > rowl) pvv = 0.f;
                        Ps[rowl * 72 + col] = f2bf(pvv);
                    }
            // wave-private strip: same-wave lgkmcnt ordering, no barrier needed
            v8s ap[2][2];
#pragma unroll
            for (int rt = 0; rt < 2; ++rt) {
                ap[rt][0] = *(const v8s*)&Ps[(w * 32 + rt * 16 + l15) * 72 + quad * 8];
                ap[rt][1] = *(const v8s*)&Ps[(w * 32 + rt * 16 + l15) * 72 + 32 + quad * 8];
            }
            __builtin_amdgcn_s_setprio(1);
#pragma unroll
            for (int ct = 0; ct < 4; ++ct) {
                v8s b0 = *(const v8s*)&Vs[(ct * 16 + l15) * 72 + quad * 8];
                v8s b1 = *(const v8s*)&Vs[(ct * 16 + l15) * 72 + 32 + quad * 8];
#pragma unroll
                for (int rt = 0; rt < 2; ++rt) {
                    o[rt][ct] = MFMA(ap[rt][0], b0, o[rt][ct]);
                    o[rt][ct] = MFMA(ap[rt][1], b1, o[rt][ct]);
                }
            }
            __builtin_amdgcn_s_setprio(0);
        }
    };

    // one pipeline step: QK(it) | stage(it+1) | prefetch(it+2) | finish(it-1)
    auto STEP = [&](int it, v4f (&scur)[2][4], v4f (&sprev)[2][4]) {
        {   // A: QK^T tile it from Kb[it&1]
            const short* Ks = Kb0 + (it & 1) * 4608;
            __builtin_amdgcn_s_setprio(1);
#pragma unroll
            for (int ct = 0; ct < 4; ++ct) {
                v8s b0 = *(const v8s*)&Ks[(ct * 16 + l15) * 72 + quad * 8];
                v8s b1 = *(const v8s*)&Ks[(ct * 16 + l15) * 72 + 32 + quad * 8];
#pragma unroll
                for (int rt = 0; rt < 2; ++rt) {
                    v4f a = 0.f;
                    a = MFMA(qf[rt][0], b0, a);
                    a = MFMA(qf[rt][1], b1, a);
                    scur[rt][ct] = a;
                }
            }
            __builtin_amdgcn_s_setprio(0);
        }
        if (it + 1 < 32) {   // B: stage tile it+1 from regs
            short* Kw = Kb0 + ((it + 1) & 1) * 4608;
            short* Vw = Vb0 + vw * 4608;
            const bool vneed = (it + 1 <= ktd);
#pragma unroll
            for (int i = 0; i < 2; ++i) {
                const int row = arow + i * 32;
                *(float4*)&Kw[row * 72 + ac] = kf[i];
                if (vneed) *(float4*)&Vw[row * 72 + ac] = vf[i];
            }
            if (it + 2 < 32) {   // C: global prefetch tile it+2
                const int T = it + 2;
#pragma unroll
                for (int i = 0; i < 2; ++i) {
                    const int row = arow + i * 32;
                    kf[i] = *(const float4*)&K[qkb + (size_t)(T * 64 + row) * DHD + ac];
                    if (T <= ktd)
                        vf[i] = *(const float4*)&Vt[vtb + (size_t)row * NS + T * 64 + ac];
                }
            }
        }
        if (it >= 1) FINISH(it - 1, sprev);   // D: independent of A -> overlaps
        vw = (vw == 2) ? 0 : vw + 1;
        vr = (vr == 2) ? 0 : vr + 1;
        __syncthreads();   // single barrier per tile
    };

    v4f sA[2][4], sB[2][4];
#pragma unroll 1
    for (int it2 = 0; it2 < 16; ++it2) {      // ping-pong: no runtime-indexed regs
        STEP(2 * it2,     sA, sB);
        STEP(2 * it2 + 1, sB, sA);
    }
    FINISH(31, sB);                            // drain: last tile's exp/PV

    // row denominators: one 16-lane reduction AFTER the loop
#pragma unroll
    for (int m = 1; m < 16; m <<= 1)
#pragma unroll
        for (int rt = 0; rt < 2; ++rt)
#pragma unroll
            for (int r = 0; r < 4; ++r)
                lpart[rt][r] += __shfl_xor(lpart[rt][r], m);

    float* Os = (float*)SMEM;            // [64][68] fp32 overlays Kb area, two half-passes
#pragma unroll
    for (int half = 0; half < 2; ++half) {
        __syncthreads();                 // previous SMEM reads done
        if ((w >> 1) == half) {          // waves {0,1} -> rows 0..63; {2,3} -> 64..127
#pragma unroll
            for (int rt = 0; rt < 2; ++rt)
#pragma unroll
                for (int r = 0; r < 4; ++r) {
                    const float inv = 1.f / lpart[rt][r];
                    const int row = (w & 1) * 32 + rt * 16 + quad * 4 + r;
#pragma unroll
                    for (int ct = 0; ct < 4; ++ct)
                        Os[row * 68 + ct * 16 + l15] = o[rt][ct][r] * inv;
                }
        }
        __syncthreads();
#pragma unroll
        for (int i = 0; i < 4; ++i) {    // coalesced float4 writes of Z
            const int f = t + i * 256;   // 1024 f4 = 64 rows x 16
            const int row = f >> 4, c4 = (f & 15) * 4;
            float4 v = *(const float4*)&Os[row * 68 + c4];
            *(float4*)&Z[((size_t)b * NS + i0 + half * 64 + row) * DM + h * DHD + c4] = v;
        }
    }
}

// ---------------- FFN GEMM (MFMA, pipelined): R = relu(X @ Wffn + b) ----------------
// grid (64, 8): block = 64 rows x 128 cols, K=1024
__global__ __launch_bounds__(256, 4) void ffn_gemm(
    const __hip_bfloat16* __restrict__ Xh, const __hip_bfloat16* __restrict__ WT,
    const float* __restrict__ bffn, float* __restrict__ R, int layer)
{
    __shared__ short As[64 * 72];
    __shared__ short Bs[128 * 72];
    const int t = threadIdx.x;
    const int wave = t >> 6, lane = t & 63, l15 = lane & 15, quad = lane >> 4;
    const int m0 = blockIdx.x * 64, n0 = blockIdx.y * 128;
    const int arow = t >> 3, ac = (t & 7) * 8;

    v4f acc[8];
#pragma unroll
    for (int i = 0; i < 8; ++i) acc[i] = 0.f;

    float4 ap[2], bp[4];
#pragma unroll
    for (int i = 0; i < 2; ++i)
        ap[i] = *(const float4*)&Xh[(size_t)(m0 + arow + i * 32) * DM + ac];
#pragma unroll
    for (int i = 0; i < 4; ++i)
        bp[i] = *(const float4*)&WT[((size_t)layer * DM + n0 + arow + i * 32) * DM + ac];

    for (int k0 = 0; k0 < DM; k0 += 64) {
        __syncthreads();
#pragma unroll
        for (int i = 0; i < 2; ++i) *(float4*)&As[(arow + i * 32) * 72 + ac] = ap[i];
#pragma unroll
        for (int i = 0; i < 4; ++i) *(float4*)&Bs[(arow + i * 32) * 72 + ac] = bp[i];
        __syncthreads();
        if (k0 + 64 < DM) {
            const int kn = k0 + 64;
#pragma unroll
            for (int i = 0; i < 2; ++i)
                ap[i] = *(const float4*)&Xh[(size_t)(m0 + arow + i * 32) * DM + kn + ac];
#pragma unroll
            for (int i = 0; i < 4; ++i)
                bp[i] = *(const float4*)&WT[((size_t)layer * DM + n0 + arow + i * 32) * DM + kn + ac];
        }

        v8s af0 = *(const v8s*)&As[(wave * 16 + l15) * 72 + quad * 8];
        v8s af1 = *(const v8s*)&As[(wave * 16 + l15) * 72 + 32 + quad * 8];
#pragma unroll
        for (int ct = 0; ct < 8; ++ct) {
            v8s b0 = *(const v8s*)&Bs[(ct * 16 + l15) * 72 + quad * 8];
            v8s b1 = *(const v8s*)&Bs[(ct * 16 + l15) * 72 + 32 + quad * 8];
            acc[ct] = MFMA(af0, b0, acc[ct]);
            acc[ct] = MFMA(af1, b1, acc[ct]);
        }
    }
#pragma unroll
    for (int ct = 0; ct < 8; ++ct) {
        const int n = n0 + ct * 16 + l15;
        const float bias = bffn[(size_t)layer * DM + n];
#pragma unroll
        for (int r = 0; r < 4; ++r) {
            const int m = m0 + wave * 16 + quad * 4 + r;
            R[(size_t)m * DM + n] = fmaxf(acc[ct][r] + bias, 0.f);
        }
    }
}

// ---------------- X = (X+R - mu) / var  (divide by VARIANCE — faithful bug) ----------------
__global__ __launch_bounds__(256) void add_ln(
    const float* __restrict__ Xin, const float* __restrict__ Rr,
    float* __restrict__ Xout, __hip_bfloat16* __restrict__ Xh)
{
    __shared__ float red[8];
    const int t = threadIdx.x;
    const size_t base = (size_t)blockIdx.x * DM;
    float4 x4 = *(const float4*)&Xin[base + t * 4];
    float4 r4 = *(const float4*)&Rr[base + t * 4];
    float v[4] = {x4.x + r4.x, x4.y + r4.y, x4.z + r4.z, x4.w + r4.w};
    float ssum = wave_sum(v[0] + v[1] + v[2] + v[3]);
    if ((t & 63) == 0) red[t >> 6] = ssum;
    __syncthreads();
    const float mu = (red[0] + red[1] + red[2] + red[3]) * (1.f / DM);
    float sq = 0.f;
#pragma unroll
    for (int i = 0; i < 4; ++i) { const float d = v[i] - mu; sq = fmaf(d, d, sq); }
    sq = wave_sum(sq);
    if ((t & 63) == 0) red[4 + (t >> 6)] = sq;
    __syncthreads();
    const float var = (red[4] + red[5] + red[6] + red[7]) * (1.f / DM);
    const float inv = 1.f / var;
    float4 o = {(v[0] - mu) * inv, (v[1] - mu) * inv, (v[2] - mu) * inv, (v[3] - mu) * inv};
    *(float4*)&Xout[base + t * 4] = o;
    union { short s[4]; float2 f2; } hb;
    hb.s[0] = f2bf(o.x); hb.s[1] = f2bf(o.y); hb.s[2] = f2bf(o.z); hb.s[3] = f2bf(o.w);
    *(float2*)&Xh[base + t * 4] = hb.f2;
}

// ---------------- last-token logits, both batches in one pass over Wout ----------------
__global__ __launch_bounds__(256) void last_logits2(
    const float* __restrict__ X, const float* __restrict__ Wout,
    const float* __restrict__ bout, float* __restrict__ logits)
{
    __shared__ float xs[2 * DM];
    const int t = threadIdx.x;
    for (int k = t; k < 2 * DM; k += 256) {
        const int bb = k >> 10, d = k & (DM - 1);
        xs[k] = X[((size_t)bb * NS + NS - 1) * DM + d];
    }
    __syncthreads();
    const int v = blockIdx.x * 256 + t;
    float a0 = bout[v], a1 = a0;
    for (int d = 0; d < DM; ++d) {
        const float w = Wout[(size_t)d * NV + v];   // coalesced; Wout read ONCE
        a0 = fmaf(xs[d], w, a0);
        a1 = fmaf(xs[DM + d], w, a1);
    }
    logits[v] = a0;
    logits[NV + v] = a1;
}

__global__ __launch_bounds__(256) void final_softmax(
    const float* __restrict__ logits, float* __restrict__ out)
{
    __shared__ float red[8];
    const int b = blockIdx.x, t = threadIdx.x;
    const float* lp = logits + b * NV;
    float mx = -1e30f;
    for (int v = t; v < NV; v += 256) mx = fmaxf(mx, lp[v]);
    mx = wave_max(mx);
    if ((t & 63) == 0) red[t >> 6] = mx;
    __syncthreads();
    mx = fmaxf(fmaxf(red[0], red[1]), fmaxf(red[2], red[3]));
    float sum = 0.f;
    for (int v = t; v < NV; v += 256) sum += __expf(lp[v] - mx);
    sum = wave_sum(sum);
    if ((t & 63) == 0) red[4 + (t >> 6)] = sum;
    __syncthreads();
    sum = red[4] + red[5] + red[6] + red[7];
    const float inv = 1.f / sum;
    for (int v = t; v < NV; v += 256) out[b * NV + v] = __expf(lp[v] - mx) * inv;
}

extern "C" void kernel_launch(void* const* d_in, const int* in_sizes, int n_in,
                              void* d_out, int out_size, void* d_ws, size_t ws_size,
                              hipStream_t stream)
{
    (void)in_sizes; (void)n_in; (void)out_size; (void)ws_size;
    const float* X_in = (const float*)d_in[0];
    const float* Wq   = (const float*)d_in[1];
    const float* Wk   = (const float*)d_in[2];
    const float* Wv   = (const float*)d_in[3];
    const float* bq   = (const float*)d_in[4];
    const float* bk   = (const float*)d_in[5];
    const float* bv   = (const float*)d_in[6];
    const float* Wffn = (const float*)d_in[7];
    const float* bffn = (const float*)d_in[8];
    const float* Wout = (const float*)d_in[9];
    const float* bout = (const float*)d_in[10];
    float* out = (float*)d_out;

    // workspace carve-up (~101 MB)
    const size_t NE = (size_t)NM * DM;
    char* p = (char*)d_ws;
    float* Xb = (float*)p;                    p += NE * 4;
    float* Rb = (float*)p;                    p += NE * 4;
    float* logits = (float*)p;                p += (size_t)NB * NV * 4;
    __hip_bfloat16* Xhi  = (__hip_bfloat16*)p; p += NE * 2;
    __hip_bfloat16* Qb   = (__hip_bfloat16*)p; p += NE * 2;
    __hip_bfloat16* Kb   = (__hip_bfloat16*)p; p += NE * 2;
    __hip_bfloat16* Vtb  = (__hip_bfloat16*)p; p += NE * 2;
    __hip_bfloat16* WqkvT = (__hip_bfloat16*)p; p += (size_t)3 * 64 * 64 * DM * 2;
    __hip_bfloat16* WffnT = (__hip_bfloat16*)p; p += (size_t)NL * DM * DM * 2;

    wqkv_transpose<<<dim3(16, 192), 256, 0, stream>>>(Wq, Wk, Wv, WqkvT);
    wffn_transpose<<<dim3(16, 16, NL), 256, 0, stream>>>(Wffn, WffnT);
    convert_x0<<<NM, 256, 0, stream>>>(X_in, Xhi);

    for (int l = 0; l < NL; ++l) {
        const float* Xcur = (l == 0) ? X_in : Xb;   // never write d_in
        qkv_gemm<<<dim3(32, 16), 256, 0, stream>>>(Xhi, WqkvT, bq, bk, bv, Qb, Kb, Vtb, l);
        attn_kernel<<<dim3(32, 16), 256, 0, stream>>>(Qb, Kb, Vtb, Rb);
        add_ln<<<NM, 256, 0, stream>>>(Xcur, Rb, Xb, Xhi);
        ffn_gemm<<<dim3(64, 8), 256, 0, stream>>>(Xhi, WffnT, bffn, Rb, l);
        add_ln<<<NM, 256, 0, stream>>>(Xb, Rb, Xb, Xhi);
    }
    last_logits2<<<NV / 256, 256, 0, stream>>>(Xb, Wout, bout, logits);
    final_softmax<<<NB, 256, 0, stream>>>(logits, out);
}

// Round 4
// 1391.933 us; speedup vs baseline: 1.0220x; 1.0220x over previous
//
#include <hip/hip_runtime.h>
#include <hip/hip_bf16.h>

#define NL 4
#define NH 16
#define DM 1024
#define DHD 64
#define NV 32000
#define NB 2
#define NS 2048
#define NM (NB * NS)   // 4096 rows

typedef __attribute__((ext_vector_type(8))) short v8s;   // 8 bf16 (4 VGPRs) MFMA A/B frag
typedef __attribute__((ext_vector_type(4))) float v4f;   // MFMA C/D frag

#define MFMA(a, b, c) __builtin_amdgcn_mfma_f32_16x16x32_bf16(a, b, c, 0, 0, 0)

__device__ __forceinline__ short f2bf(float x) {
    __hip_bfloat16 h = __float2bfloat16(x);   // RNE
    return *reinterpret_cast<short*>(&h);
}
__device__ __forceinline__ float wave_sum(float v) {
    v += __shfl_xor(v, 32); v += __shfl_xor(v, 16); v += __shfl_xor(v, 8);
    v += __shfl_xor(v, 4);  v += __shfl_xor(v, 2);  v += __shfl_xor(v, 1);
    return v;
}
__device__ __forceinline__ float wave_max(float v) {
    v = fmaxf(v, __shfl_xor(v, 32)); v = fmaxf(v, __shfl_xor(v, 16));
    v = fmaxf(v, __shfl_xor(v, 8));  v = fmaxf(v, __shfl_xor(v, 4));
    v = fmaxf(v, __shfl_xor(v, 2));  v = fmaxf(v, __shfl_xor(v, 1));
    return v;
}

// ---------------- one-time weight prep (per call; graph-safe) ----------------
// Wq/Wk/Wv [LH][1024][64] fp32 -> WT bf16 [which*64+lh][64 dh][1024 k]
__global__ __launch_bounds__(256) void wqkv_transpose(
    const float* __restrict__ Wq, const float* __restrict__ Wk,
    const float* __restrict__ Wv, __hip_bfloat16* __restrict__ WT)
{
    __shared__ float T[64][68];
    const int t = threadIdx.x;
    const int k0 = blockIdx.x * 64;
    const int y = blockIdx.y;                 // which*64 + lh
    const int which = y >> 6, lh = y & 63;
    const float* W = (which == 0 ? Wq : which == 1 ? Wk : Wv)
                     + ((size_t)lh * DM + k0) * DHD;
#pragma unroll
    for (int i = 0; i < 4; ++i) {
        const int f = t + i * 256;            // 1024 float4 = 64 k-rows x 16
        const int kr = f >> 4, c = (f & 15) * 4;
        float4 w4 = *(const float4*)&W[(size_t)kr * DHD + c];
        T[kr][c + 0] = w4.x; T[kr][c + 1] = w4.y;
        T[kr][c + 2] = w4.z; T[kr][c + 3] = w4.w;
    }
    __syncthreads();
#pragma unroll
    for (int i = 0; i < 2; ++i) {
        const int f = t + i * 256;            // 512 chunks: 64 n-rows x 8
        const int n = f >> 3, c = (f & 7) * 8;
        short tmp[8];
#pragma unroll
        for (int j = 0; j < 8; ++j) tmp[j] = f2bf(T[c + j][n]);
        *(float4*)&WT[(((size_t)y) * 64 + n) * DM + k0 + c] = *(float4*)tmp;
    }
}

// Wffn [L][1024][1024] fp32 -> WT bf16 [l][1024 n][1024 k]
__global__ __launch_bounds__(256) void wffn_transpose(
    const float* __restrict__ Wffn, __hip_bfloat16* __restrict__ WT)
{
    __shared__ float T[64][68];
    const int t = threadIdx.x;
    const int k0 = blockIdx.x * 64, n0 = blockIdx.y * 64, l = blockIdx.z;
    const float* W = Wffn + ((size_t)l * DM + k0) * DM + n0;
#pragma unroll
    for (int i = 0; i < 4; ++i) {
        const int f = t + i * 256;
        const int kr = f >> 4, c = (f & 15) * 4;
        float4 w4 = *(const float4*)&W[(size_t)kr * DM + c];
        T[kr][c + 0] = w4.x; T[kr][c + 1] = w4.y;
        T[kr][c + 2] = w4.z; T[kr][c + 3] = w4.w;
    }
    __syncthreads();
#pragma unroll
    for (int i = 0; i < 2; ++i) {
        const int f = t + i * 256;
        const int n = f >> 3, c = (f & 7) * 8;
        short tmp[8];
#pragma unroll
        for (int j = 0; j < 8; ++j) tmp[j] = f2bf(T[c + j][n]);
        *(float4*)&WT[((size_t)l * DM + n0 + n) * DM + k0 + c] = *(float4*)tmp;
    }
}

__global__ __launch_bounds__(256) void convert_x0(
    const float* __restrict__ X, __hip_bfloat16* __restrict__ Xh)
{
    const size_t i = ((size_t)blockIdx.x * 256 + threadIdx.x) * 4;
    float4 x = *(const float4*)&X[i];
    union { short s[4]; float2 f2; } hb;
    hb.s[0] = f2bf(x.x); hb.s[1] = f2bf(x.y); hb.s[2] = f2bf(x.z); hb.s[3] = f2bf(x.w);
    *(float2*)&Xh[i] = hb.f2;
}

// ---------------- QKV projection (MFMA, pipelined staging) ----------------
// grid (32, 16): logical block = 128 rows x 192 cols (q|k|v of head h), K=1024.
// (m,h) remapped so each XCD's resident cell = 8 m-tiles x 8 heads (L2-resident).
// Q/K outputs staged via LDS -> full-line float4 row writes.
__global__ __launch_bounds__(256, 2) void qkv_gemm(
    const __hip_bfloat16* __restrict__ Xh, const __hip_bfloat16* __restrict__ WT,
    const float* __restrict__ bq, const float* __restrict__ bk,
    const float* __restrict__ bv,
    __hip_bfloat16* __restrict__ Q, __hip_bfloat16* __restrict__ K,
    __hip_bfloat16* __restrict__ Vt, int layer)
{
    __shared__ short As[128 * 72];   // X tile [128 m][64 k]; epilogue: Q [128 m][64 dh]
    __shared__ short Bs[192 * 72];   // W^T tile [192 n][64 k]; epilogue: K [128 m][64 dh]
    __shared__ short Vst[64 * 136];  // epilogue: V^T [64 d][128 s]
    const int t = threadIdx.x;
    const int wave = t >> 6, lane = t & 63, l15 = lane & 15, quad = lane >> 4;
    const int id = blockIdx.y * 32 + blockIdx.x;       // XCD = id % 8
    const int x8 = id & 7, j = id >> 3;
    const int m0 = ((x8 & 3) * 8 + (j & 7)) * 128;     // 8 m-tiles per XCD cell
    const int h = (x8 >> 2) * 8 + (j >> 3);            // 8 heads per XCD cell
    const int lh = layer * NH + h;
    const int arow = t >> 3, ac = (t & 7) * 8;

    v4f acc[2][12];
#pragma unroll
    for (int i = 0; i < 2; ++i)
#pragma unroll
        for (int j2 = 0; j2 < 12; ++j2) acc[i][j2] = 0.f;

    float4 ap[4], bp[6];
#pragma unroll
    for (int i = 0; i < 4; ++i)
        ap[i] = *(const float4*)&Xh[(size_t)(m0 + arow + i * 32) * DM + ac];
#pragma unroll
    for (int i = 0; i < 6; ++i) {
        const int row = arow + i * 32;
        const int which = row >> 6, dh = row & 63;
        bp[i] = *(const float4*)&WT[(((size_t)which * 64 + lh) * 64 + dh) * DM + ac];
    }

    for (int k0 = 0; k0 < DM; k0 += 64) {
        __syncthreads();
#pragma unroll
        for (int i = 0; i < 4; ++i) *(float4*)&As[(arow + i * 32) * 72 + ac] = ap[i];
#pragma unroll
        for (int i = 0; i < 6; ++i) *(float4*)&Bs[(arow + i * 32) * 72 + ac] = bp[i];
        __syncthreads();
        if (k0 + 64 < DM) {                   // prefetch next k-chunk during compute
            const int kn = k0 + 64;
#pragma unroll
            for (int i = 0; i < 4; ++i)
                ap[i] = *(const float4*)&Xh[(size_t)(m0 + arow + i * 32) * DM + kn + ac];
#pragma unroll
            for (int i = 0; i < 6; ++i) {
                const int row = arow + i * 32;
                const int which = row >> 6, dh = row & 63;
                bp[i] = *(const float4*)&WT[(((size_t)which * 64 + lh) * 64 + dh) * DM + kn + ac];
            }
        }

        v8s af[2][2];
#pragma unroll
        for (int rt = 0; rt < 2; ++rt)
#pragma unroll
            for (int kh = 0; kh < 2; ++kh)
                af[rt][kh] = *(const v8s*)&As[(wave * 32 + rt * 16 + l15) * 72 + kh * 32 + quad * 8];
#pragma unroll
        for (int ct = 0; ct < 12; ++ct) {
            v8s b0 = *(const v8s*)&Bs[(ct * 16 + l15) * 72 + quad * 8];
            v8s b1 = *(const v8s*)&Bs[(ct * 16 + l15) * 72 + 32 + quad * 8];
#pragma unroll
            for (int rt = 0; rt < 2; ++rt) {
                acc[rt][ct] = MFMA(af[rt][0], b0, acc[rt][ct]);
                acc[rt][ct] = MFMA(af[rt][1], b1, acc[rt][ct]);
            }
        }
    }

    // ---- epilogue: stage Q->As, K->Bs, V^T->Vst; then full-line coalesced writes ----
    __syncthreads();                      // all MFMA frag reads of As/Bs done
#pragma unroll
    for (int ct = 0; ct < 4; ++ct) {      // Q: [m][dh]
        const float bias = bq[(size_t)lh * DHD + ct * 16 + l15];
#pragma unroll
        for (int rt = 0; rt < 2; ++rt)
#pragma unroll
            for (int r = 0; r < 4; ++r) {
                const int row = wave * 32 + rt * 16 + quad * 4 + r;
                As[row * 72 + ct * 16 + l15] = f2bf(acc[rt][ct][r] + bias);
            }
    }
#pragma unroll
    for (int ct = 4; ct < 8; ++ct) {      // K: [m][dh]
        const float bias = bk[(size_t)lh * DHD + (ct - 4) * 16 + l15];
#pragma unroll
        for (int rt = 0; rt < 2; ++rt)
#pragma unroll
            for (int r = 0; r < 4; ++r) {
                const int row = wave * 32 + rt * 16 + quad * 4 + r;
                Bs[row * 72 + (ct - 4) * 16 + l15] = f2bf(acc[rt][ct][r] + bias);
            }
    }
#pragma unroll
    for (int ct = 8; ct < 12; ++ct) {     // V^T: [d][s]
        const int d = (ct - 8) * 16 + l15;
        const float bias = bv[(size_t)lh * DHD + d];
#pragma unroll
        for (int rt = 0; rt < 2; ++rt)
#pragma unroll
            for (int r = 0; r < 4; ++r) {
                const int srow = wave * 32 + rt * 16 + quad * 4 + r;
                Vst[d * 136 + srow] = f2bf(acc[rt][ct][r] + bias);
            }
    }
    __syncthreads();
#pragma unroll
    for (int i = 0; i < 4; ++i) {         // Q,K: 128 rows x 8 float4 (full 128-B rows)
        const int f = t + i * 256;
        const int row = f >> 3, c = (f & 7) * 8;
        const int m = m0 + row, bb = m >> 11, s = m & (NS - 1);
        const size_t base = ((size_t)(bb * NH + h) * NS + s) * DHD + c;
        *(float4*)&Q[base] = *(const float4*)&As[row * 72 + c];
        *(float4*)&K[base] = *(const float4*)&Bs[row * 72 + c];
    }
    const int bblk = m0 >> 11;            // block never spans batch (2048 % 128 == 0)
    const int s0 = m0 & (NS - 1);
    const size_t vtb = (size_t)(bblk * NH + h) * DHD * NS;
#pragma unroll
    for (int i = 0; i < 4; ++i) {         // V^T: 64 d-rows x 16 float4
        const int f = t + i * 256;
        const int d = f >> 4, c = (f & 15) * 8;
        *(float4*)&Vt[vtb + (size_t)d * NS + s0 + c] = *(const float4*)&Vst[d * 136 + c];
    }
}

// ---------------- attention (MFMA flash, faithful softmax-then-tril, SPLIT-K x2) -------
// grid (32 bh, 32 y): y -> (half = y>>4, yt = y&15); bi = (yt<8)?yt:23-yt; 128 q rows.
// Each block handles 16 of 32 key tiles -> 1024 blocks = 4/CU = 16 waves/CU (2x TLP
// vs round 2; round-3 ILP pipeline failed, so TLP is the lever).
// blockIdx.x = bh -> all blocks of one (b,h) on ONE XCD (K/V L2-resident).
// Co-resident window {y0,y0+8,y0+16,y0+24} has constant 34 PV-tiles (balanced).
// Partials: Op = raw o (fp32), Lp = denominator partials; combine fused in add_ln_attn.
// Causality: half-1 o is nonzero only for q rows >= 1024 -> Op1 is half-size.
// FIXED-max softmax (scores O(1)); denominator over ALL tiles (faithful bug);
// tril masks P only; PV skipped for fully-masked tiles.
__global__ __launch_bounds__(256, 4) void attn_kernel(
    const __hip_bfloat16* __restrict__ Q, const __hip_bfloat16* __restrict__ K,
    const __hip_bfloat16* __restrict__ Vt,
    float* __restrict__ Op0, float* __restrict__ Op1, float* __restrict__ Lp)
{
    __shared__ short SMEM[2 * 64 * 72 + 128 * 72];   // Ks | Vs | Ps ; epilogue fp32 Os[64][68]
    short* Ks = SMEM;
    short* Vs = SMEM + 64 * 72;
    short* Ps = SMEM + 2 * 64 * 72;
    const int t = threadIdx.x;
    const int w = t >> 6, lane = t & 63, l15 = lane & 15, quad = lane >> 4;
    const int bh = blockIdx.x;
    const int y = blockIdx.y;
    const int half = y >> 4;                         // key half: tiles [half*16, half*16+16)
    const int yt = y & 15;
    const int bi = (yt < 8) ? yt : (23 - yt);        // co-resident pair sums to 15
    const int i0 = bi * 128;
    const int b = bh >> 4, h = bh & 15;
    const size_t qkb = (size_t)bh * NS * DHD;
    const size_t vtb = (size_t)bh * DHD * NS;
    const int arow = t >> 3, ac = (t & 7) * 8;
    const int ktd = 2 * bi + 1;                      // last global tile with PV
    const int kt0 = half * 16, kt1 = kt0 + 16;
    const bool havePV = (ktd >= kt0);                // block-uniform

    // Q fragments for this wave's 32 rows, straight from global (loop-invariant)
    v8s aq[2][2];
#pragma unroll
    for (int rt = 0; rt < 2; ++rt) {
        const size_t qrow = qkb + (size_t)(i0 + w * 32 + rt * 16 + l15) * DHD + quad * 8;
        aq[rt][0] = *(const v8s*)&Q[qrow];
        aq[rt][1] = *(const v8s*)&Q[qrow + 32];
    }

    v4f o[2][4];
    float lpart[2][4];
#pragma unroll
    for (int rt = 0; rt < 2; ++rt)
#pragma unroll
        for (int i = 0; i < 4; ++i) { o[rt][i] = 0.f; lpart[rt][i] = 0.f; }

    float4 kf[2], vf[2];                 // prefetch tile kt0
#pragma unroll
    for (int i = 0; i < 2; ++i) {
        const int row = arow + i * 32;
        kf[i] = *(const float4*)&K[qkb + (size_t)(kt0 * 64 + row) * DHD + ac];
        if (kt0 <= ktd)
            vf[i] = *(const float4*)&Vt[vtb + (size_t)row * NS + kt0 * 64 + ac];
    }

    for (int kt = kt0; kt < kt1; ++kt) { // NEVER early-exit: l needs full half
        const bool pv = (kt <= ktd);     // block-uniform
        __syncthreads();                 // prev tile's frag reads done
#pragma unroll
        for (int i = 0; i < 2; ++i) {
            const int row = arow + i * 32;
            *(float4*)&Ks[row * 72 + ac] = kf[i];
            if (pv) *(float4*)&Vs[row * 72 + ac] = vf[i];
        }
        __syncthreads();                 // tiles staged
        if (kt + 1 < kt1) {              // prefetch next tile during compute
            const int nt = kt + 1;
#pragma unroll
            for (int i = 0; i < 2; ++i) {
                const int row = arow + i * 32;
                kf[i] = *(const float4*)&K[qkb + (size_t)(nt * 64 + row) * DHD + ac];
                if (nt <= ktd)           // V only needed for unmasked tiles
                    vf[i] = *(const float4*)&Vt[vtb + (size_t)row * NS + nt * 64 + ac];
            }
        }

        // QK^T on matrix cores: each K fragment feeds both row-tiles
        v4f s[2][4];
#pragma unroll
        for (int ct = 0; ct < 4; ++ct) {
            v8s b0 = *(const v8s*)&Ks[(ct * 16 + l15) * 72 + quad * 8];
            v8s b1 = *(const v8s*)&Ks[(ct * 16 + l15) * 72 + 32 + quad * 8];
#pragma unroll
            for (int rt = 0; rt < 2; ++rt) {
                v4f a = 0.f;
                a = MFMA(aq[rt][0], b0, a);
                a = MFMA(aq[rt][1], b1, a);
                s[rt][ct] = a;
            }
        }
        // p = exp(s/8) with fixed max; denominator partials stay per-thread
#pragma unroll
        for (int rt = 0; rt < 2; ++rt) {
#pragma unroll
            for (int ct = 0; ct < 4; ++ct)
#pragma unroll
                for (int r = 0; r < 4; ++r)
                    s[rt][ct][r] = __expf(s[rt][ct][r] * 0.125f);
#pragma unroll
            for (int r = 0; r < 4; ++r)
                lpart[rt][r] += s[rt][0][r] + s[rt][1][r] + s[rt][2][r] + s[rt][3][r];
        }

        if (pv) {
            const int dk = kt - 2 * bi;  // 0 or 1 on diagonal tiles, else negative
#pragma unroll
            for (int rt = 0; rt < 2; ++rt)
#pragma unroll
                for (int ct = 0; ct < 4; ++ct)
#pragma unroll
                    for (int r = 0; r < 4; ++r) {
                        const int rowl = w * 32 + rt * 16 + quad * 4 + r;  // q in block
                        const int col = ct * 16 + l15;                     // key in tile
                        float pvv = s[rt][ct][r];
                        if (dk >= 0 && dk * 64 + col > rowl) pvv = 0.f;    // tril mask
                        Ps[rowl * 72 + col] = f2bf(pvv);
                    }
            // wave-private strips: same-wave lgkmcnt ordering, no barrier needed
            v8s ap[2][2];
#pragma unroll
            for (int rt = 0; rt < 2; ++rt) {
                ap[rt][0] = *(const v8s*)&Ps[(w * 32 + rt * 16 + l15) * 72 + quad * 8];
                ap[rt][1] = *(const v8s*)&Ps[(w * 32 + rt * 16 + l15) * 72 + 32 + quad * 8];
            }
#pragma unroll
            for (int ct = 0; ct < 4; ++ct) {
                v8s b0 = *(const v8s*)&Vs[(ct * 16 + l15) * 72 + quad * 8];
                v8s b1 = *(const v8s*)&Vs[(ct * 16 + l15) * 72 + 32 + quad * 8];
#pragma unroll
                for (int rt = 0; rt < 2; ++rt) {
                    o[rt][ct] = MFMA(ap[rt][0], b0, o[rt][ct]);
                    o[rt][ct] = MFMA(ap[rt][1], b1, o[rt][ct]);
                }
            }
        }
    }

    // row denominator partials: one 16-lane reduction AFTER the loop
#pragma unroll
    for (int m = 1; m < 16; m <<= 1)
#pragma unroll
        for (int rt = 0; rt < 2; ++rt)
#pragma unroll
            for (int r = 0; r < 4; ++r)
                lpart[rt][r] += __shfl_xor(lpart[rt][r], m);

    if (l15 == 0) {                      // Lp[half][bh][row]: 4 lanes/wave x 8 values
#pragma unroll
        for (int rt = 0; rt < 2; ++rt)
#pragma unroll
            for (int r = 0; r < 4; ++r) {
                const int row = i0 + w * 32 + rt * 16 + quad * 4 + r;
                Lp[((size_t)half * 32 + bh) * NS + row] = lpart[rt][r];
            }
    }

    if (!havePV) return;                 // block-uniform; o is all zeros

    float* Os = (float*)SMEM;            // [64][68] fp32 overlays SMEM, two half-passes
#pragma unroll
    for (int hp = 0; hp < 2; ++hp) {
        __syncthreads();                 // previous SMEM reads done
        if ((w >> 1) == hp) {            // waves {0,1} -> rows 0..63; {2,3} -> 64..127
#pragma unroll
            for (int rt = 0; rt < 2; ++rt)
#pragma unroll
                for (int r = 0; r < 4; ++r) {
                    const int row = (w & 1) * 32 + rt * 16 + quad * 4 + r;
#pragma unroll
                    for (int ct = 0; ct < 4; ++ct)
                        Os[row * 68 + ct * 16 + l15] = o[rt][ct][r];   // raw, unscaled
                }
        }
        __syncthreads();
#pragma unroll
        for (int i = 0; i < 4; ++i) {    // coalesced float4 writes of Op
            const int f = t + i * 256;   // 1024 f4 = 64 rows x 16
            const int row = f >> 4, c4 = (f & 15) * 4;
            float4 v = *(const float4*)&Os[row * 68 + c4];
            const int srow = i0 + hp * 64 + row;
            if (half == 0)
                *(float4*)&Op0[((size_t)bh * NS + srow) * DHD + c4] = v;
            else
                *(float4*)&Op1[((size_t)bh * 1024 + (srow - 1024)) * DHD + c4] = v;
        }
    }
}

// ---------------- FFN GEMM (MFMA, pipelined): R = relu(X @ Wffn + b) ----------------
// grid (64, 8): block = 64 rows x 128 cols, K=1024
__global__ __launch_bounds__(256, 4) void ffn_gemm(
    const __hip_bfloat16* __restrict__ Xh, const __hip_bfloat16* __restrict__ WT,
    const float* __restrict__ bffn, float* __restrict__ R, int layer)
{
    __shared__ short As[64 * 72];
    __shared__ short Bs[128 * 72];
    const int t = threadIdx.x;
    const int wave = t >> 6, lane = t & 63, l15 = lane & 15, quad = lane >> 4;
    const int m0 = blockIdx.x * 64, n0 = blockIdx.y * 128;
    const int arow = t >> 3, ac = (t & 7) * 8;

    v4f acc[8];
#pragma unroll
    for (int i = 0; i < 8; ++i) acc[i] = 0.f;

    float4 ap[2], bp[4];
#pragma unroll
    for (int i = 0; i < 2; ++i)
        ap[i] = *(const float4*)&Xh[(size_t)(m0 + arow + i * 32) * DM + ac];
#pragma unroll
    for (int i = 0; i < 4; ++i)
        bp[i] = *(const float4*)&WT[((size_t)layer * DM + n0 + arow + i * 32) * DM + ac];

    for (int k0 = 0; k0 < DM; k0 += 64) {
        __syncthreads();
#pragma unroll
        for (int i = 0; i < 2; ++i) *(float4*)&As[(arow + i * 32) * 72 + ac] = ap[i];
#pragma unroll
        for (int i = 0; i < 4; ++i) *(float4*)&Bs[(arow + i * 32) * 72 + ac] = bp[i];
        __syncthreads();
        if (k0 + 64 < DM) {
            const int kn = k0 + 64;
#pragma unroll
            for (int i = 0; i < 2; ++i)
                ap[i] = *(const float4*)&Xh[(size_t)(m0 + arow + i * 32) * DM + kn + ac];
#pragma unroll
            for (int i = 0; i < 4; ++i)
                bp[i] = *(const float4*)&WT[((size_t)layer * DM + n0 + arow + i * 32) * DM + kn + ac];
        }

        v8s af0 = *(const v8s*)&As[(wave * 16 + l15) * 72 + quad * 8];
        v8s af1 = *(const v8s*)&As[(wave * 16 + l15) * 72 + 32 + quad * 8];
#pragma unroll
        for (int ct = 0; ct < 8; ++ct) {
            v8s b0 = *(const v8s*)&Bs[(ct * 16 + l15) * 72 + quad * 8];
            v8s b1 = *(const v8s*)&Bs[(ct * 16 + l15) * 72 + 32 + quad * 8];
            acc[ct] = MFMA(af0, b0, acc[ct]);
            acc[ct] = MFMA(af1, b1, acc[ct]);
        }
    }
#pragma unroll
    for (int ct = 0; ct < 8; ++ct) {
        const int n = n0 + ct * 16 + l15;
        const float bias = bffn[(size_t)layer * DM + n];
#pragma unroll
        for (int r = 0; r < 4; ++r) {
            const int m = m0 + wave * 16 + quad * 4 + r;
            R[(size_t)m * DM + n] = fmaxf(acc[ct][r] + bias, 0.f);
        }
    }
}

// ------- attn combine + X = (X+Z - mu) / var  (divide by VARIANCE — faithful bug) -------
__global__ __launch_bounds__(256) void add_ln_attn(
    const float* __restrict__ Xin, const float* __restrict__ Op0,
    const float* __restrict__ Op1, const float* __restrict__ Lp,
    float* __restrict__ Xout, __hip_bfloat16* __restrict__ Xh)
{
    __shared__ float red[8];
    const int t = threadIdx.x;
    const int row = blockIdx.x;
    const int b = row >> 11, s = row & (NS - 1);
    const size_t base = (size_t)row * DM;
    const int d = t * 4, h = d >> 6, dh = d & 63;
    const int bh = b * NH + h;

    float4 x4 = *(const float4*)&Xin[base + d];
    float4 o4 = *(const float4*)&Op0[((size_t)bh * NS + s) * DHD + dh];
    if (s >= 1024) {
        float4 o1 = *(const float4*)&Op1[((size_t)bh * 1024 + (s - 1024)) * DHD + dh];
        o4.x += o1.x; o4.y += o1.y; o4.z += o1.z; o4.w += o1.w;
    }
    const float l = Lp[(size_t)bh * NS + s] + Lp[((size_t)32 + bh) * NS + s];
    const float invl = 1.f / l;
    float v[4] = {x4.x + o4.x * invl, x4.y + o4.y * invl,
                  x4.z + o4.z * invl, x4.w + o4.w * invl};

    float ssum = wave_sum(v[0] + v[1] + v[2] + v[3]);
    if ((t & 63) == 0) red[t >> 6] = ssum;
    __syncthreads();
    const float mu = (red[0] + red[1] + red[2] + red[3]) * (1.f / DM);
    float sq = 0.f;
#pragma unroll
    for (int i = 0; i < 4; ++i) { const float dd = v[i] - mu; sq = fmaf(dd, dd, sq); }
    sq = wave_sum(sq);
    if ((t & 63) == 0) red[4 + (t >> 6)] = sq;
    __syncthreads();
    const float var = (red[4] + red[5] + red[6] + red[7]) * (1.f / DM);
    const float inv = 1.f / var;
    float4 o = {(v[0] - mu) * inv, (v[1] - mu) * inv, (v[2] - mu) * inv, (v[3] - mu) * inv};
    *(float4*)&Xout[base + d] = o;
    union { short sb[4]; float2 f2; } hb;
    hb.sb[0] = f2bf(o.x); hb.sb[1] = f2bf(o.y); hb.sb[2] = f2bf(o.z); hb.sb[3] = f2bf(o.w);
    *(float2*)&Xh[base + d] = hb.f2;
}

// ---------------- X = (X+R - mu) / var  (divide by VARIANCE — faithful bug) ----------------
__global__ __launch_bounds__(256) void add_ln(
    const float* __restrict__ Xin, const float* __restrict__ Rr,
    float* __restrict__ Xout, __hip_bfloat16* __restrict__ Xh)
{
    __shared__ float red[8];
    const int t = threadIdx.x;
    const size_t base = (size_t)blockIdx.x * DM;
    float4 x4 = *(const float4*)&Xin[base + t * 4];
    float4 r4 = *(const float4*)&Rr[base + t * 4];
    float v[4] = {x4.x + r4.x, x4.y + r4.y, x4.z + r4.z, x4.w + r4.w};
    float ssum = wave_sum(v[0] + v[1] + v[2] + v[3]);
    if ((t & 63) == 0) red[t >> 6] = ssum;
    __syncthreads();
    const float mu = (red[0] + red[1] + red[2] + red[3]) * (1.f / DM);
    float sq = 0.f;
#pragma unroll
    for (int i = 0; i < 4; ++i) { const float d = v[i] - mu; sq = fmaf(d, d, sq); }
    sq = wave_sum(sq);
    if ((t & 63) == 0) red[4 + (t >> 6)] = sq;
    __syncthreads();
    const float var = (red[4] + red[5] + red[6] + red[7]) * (1.f / DM);
    const float inv = 1.f / var;
    float4 o = {(v[0] - mu) * inv, (v[1] - mu) * inv, (v[2] - mu) * inv, (v[3] - mu) * inv};
    *(float4*)&Xout[base + t * 4] = o;
    union { short s[4]; float2 f2; } hb;
    hb.s[0] = f2bf(o.x); hb.s[1] = f2bf(o.y); hb.s[2] = f2bf(o.z); hb.s[3] = f2bf(o.w);
    *(float2*)&Xh[base + t * 4] = hb.f2;
}

// ---------------- last-token logits, both batches in one pass over Wout ----------------
__global__ __launch_bounds__(256) void last_logits2(
    const float* __restrict__ X, const float* __restrict__ Wout,
    const float* __restrict__ bout, float* __restrict__ logits)
{
    __shared__ float xs[2 * DM];
    const int t = threadIdx.x;
    for (int k = t; k < 2 * DM; k += 256) {
        const int bb = k >> 10, d = k & (DM - 1);
        xs[k] = X[((size_t)bb * NS + NS - 1) * DM + d];
    }
    __syncthreads();
    const int v = blockIdx.x * 256 + t;
    float a0 = bout[v], a1 = a0;
    for (int d = 0; d < DM; ++d) {
        const float w = Wout[(size_t)d * NV + v];   // coalesced; Wout read ONCE
        a0 = fmaf(xs[d], w, a0);
        a1 = fmaf(xs[DM + d], w, a1);
    }
    logits[v] = a0;
    logits[NV + v] = a1;
}

__global__ __launch_bounds__(256) void final_softmax(
    const float* __restrict__ logits, float* __restrict__ out)
{
    __shared__ float red[8];
    const int b = blockIdx.x, t = threadIdx.x;
    const float* lp = logits + b * NV;
    float mx = -1e30f;
    for (int v = t; v < NV; v += 256) mx = fmaxf(mx, lp[v]);
    mx = wave_max(mx);
    if ((t & 63) == 0) red[t >> 6] = mx;
    __syncthreads();
    mx = fmaxf(fmaxf(red[0], red[1]), fmaxf(red[2], red[3]));
    float sum = 0.f;
    for (int v = t; v < NV; v += 256) sum += __expf(lp[v] - mx);
    sum = wave_sum(sum);
    if ((t & 63) == 0) red[4 + (t >> 6)] = sum;
    __syncthreads();
    sum = red[4] + red[5] + red[6] + red[7];
    const float inv = 1.f / sum;
    for (int v = t; v < NV; v += 256) out[b * NV + v] = __expf(lp[v] - mx) * inv;
}

extern "C" void kernel_launch(void* const* d_in, const int* in_sizes, int n_in,
                              void* d_out, int out_size, void* d_ws, size_t ws_size,
                              hipStream_t stream)
{
    (void)in_sizes; (void)n_in; (void)out_size; (void)ws_size;
    const float* X_in = (const float*)d_in[0];
    const float* Wq   = (const float*)d_in[1];
    const float* Wk   = (const float*)d_in[2];
    const float* Wv   = (const float*)d_in[3];
    const float* bq   = (const float*)d_in[4];
    const float* bk   = (const float*)d_in[5];
    const float* bv   = (const float*)d_in[6];
    const float* Wffn = (const float*)d_in[7];
    const float* bffn = (const float*)d_in[8];
    const float* Wout = (const float*)d_in[9];
    const float* bout = (const float*)d_in[10];
    float* out = (float*)d_out;

    // workspace carve-up (~110 MB)
    const size_t NE = (size_t)NM * DM;
    char* p = (char*)d_ws;
    float* Xb = (float*)p;                    p += NE * 4;
    // Op0 doubles as FFN's R (disjoint lifetimes within a layer)
    float* Op0 = (float*)p;                   p += (size_t)32 * NS * DHD * 4;    // 16.8 MB
    float* Rb  = Op0;
    float* Op1 = (float*)p;                   p += (size_t)32 * 1024 * DHD * 4;  // 8.4 MB
    float* Lp  = (float*)p;                   p += (size_t)2 * 32 * NS * 4;      // 0.5 MB
    float* logits = (float*)p;                p += (size_t)NB * NV * 4;
    __hip_bfloat16* Xhi  = (__hip_bfloat16*)p; p += NE * 2;
    __hip_bfloat16* Qb   = (__hip_bfloat16*)p; p += NE * 2;
    __hip_bfloat16* Kb   = (__hip_bfloat16*)p; p += NE * 2;
    __hip_bfloat16* Vtb  = (__hip_bfloat16*)p; p += NE * 2;
    __hip_bfloat16* WqkvT = (__hip_bfloat16*)p; p += (size_t)3 * 64 * 64 * DM * 2;
    __hip_bfloat16* WffnT = (__hip_bfloat16*)p; p += (size_t)NL * DM * DM * 2;

    wqkv_transpose<<<dim3(16, 192), 256, 0, stream>>>(Wq, Wk, Wv, WqkvT);
    wffn_transpose<<<dim3(16, 16, NL), 256, 0, stream>>>(Wffn, WffnT);
    convert_x0<<<NM, 256, 0, stream>>>(X_in, Xhi);

    for (int l = 0; l < NL; ++l) {
        const float* Xcur = (l == 0) ? X_in : Xb;   // never write d_in
        qkv_gemm<<<dim3(32, 16), 256, 0, stream>>>(Xhi, WqkvT, bq, bk, bv, Qb, Kb, Vtb, l);
        attn_kernel<<<dim3(32, 32), 256, 0, stream>>>(Qb, Kb, Vtb, Op0, Op1, Lp);
        add_ln_attn<<<NM, 256, 0, stream>>>(Xcur, Op0, Op1, Lp, Xb, Xhi);
        ffn_gemm<<<dim3(64, 8), 256, 0, stream>>>(Xhi, WffnT, bffn, Rb, l);
        add_ln<<<NM, 256, 0, stream>>>(Xb, Rb, Xb, Xhi);
    }
    last_logits2<<<NV / 256, 256, 0, stream>>>(Xb, Wout, bout, logits);
    final_softmax<<<NB, 256, 0, stream>>>(logits, out);
}